// Round 4
// baseline (279.485 us; speedup 1.0000x reference)
//
#include <hip/hip_runtime.h>
#include <math.h>

// MMD loss via split-bf16 MFMA, pre-split operands + global_load_lds staging.
// N²·MMD = Σ_{i,j} s_i s_j exp(-||z_i - z_j||²/D²), z = [a;b], s = [+1;-1].
// Signed Gram sum is symmetric => upper-triangular 128x128 tiles only
// (off-diagonal ×2). Dots: x·y ≈ xh·yh + xh·yl + xl·yh (bf16 split);
// |dot err| ~2e-4 -> exp-arg err ~6e-9 (<< fp32 roundoff). Norms exact fp32.

#define NPTS  8192
#define DIM   256
#define MTOT  (2 * NPTS)                  // 16384
#define TILE  128
#define BK    32
#define NTILE (MTOT / TILE)               // 128
#define XTILE (NPTS / TILE)               // 64: tiles [0,64) are 'a', rest 'b'
#define NTRI  (NTILE * (NTILE + 1) / 2)   // 8256

typedef short bf16x8 __attribute__((ext_vector_type(8)));   // 8 bf16 = 4 VGPR
typedef float f32x4  __attribute__((ext_vector_type(4)));   // MFMA C/D

// async global->LDS, 16B per lane; LDS dest = wave-uniform base + lane*16 (HW)
#define GLDS(g, l)                                                          \
    __builtin_amdgcn_global_load_lds(                                       \
        (const __attribute__((address_space(1))) void*)(g),                 \
        (__attribute__((address_space(3))) void*)(l), 16, 0, 0)

// ---------- prep: fp32 -> bf16 hi/lo split + exact fp32 norms ----------
__global__ __launch_bounds__(256) void mmd_prep(const float* __restrict__ a,
                                                const float* __restrict__ b,
                                                ushort* __restrict__ zhi,
                                                ushort* __restrict__ zlo,
                                                float* __restrict__ norms) {
    const int row  = blockIdx.x * 4 + (threadIdx.x >> 6);   // one wave per row
    const int lane = threadIdx.x & 63;
    const float* src = (row < NPTS) ? (a + (size_t)row * DIM)
                                    : (b + (size_t)(row - NPTS) * DIM);
    float4 v = *reinterpret_cast<const float4*>(src + lane * 4);
    float s = v.x * v.x + v.y * v.y + v.z * v.z + v.w * v.w;

    uint hx = __float_as_uint(v.x) & 0xFFFF0000u,
         hy = __float_as_uint(v.y) & 0xFFFF0000u,
         hz = __float_as_uint(v.z) & 0xFFFF0000u,
         hw = __float_as_uint(v.w) & 0xFFFF0000u;
    float lxf = v.x - __uint_as_float(hx), lyf = v.y - __uint_as_float(hy),
          lzf = v.z - __uint_as_float(hz), lwf = v.w - __uint_as_float(hw);
    uint2 hp = make_uint2((hx >> 16) | hy, (hz >> 16) | hw);
    uint2 lp = make_uint2((__float_as_uint(lxf) >> 16) | (__float_as_uint(lyf) & 0xFFFF0000u),
                          (__float_as_uint(lzf) >> 16) | (__float_as_uint(lwf) & 0xFFFF0000u));
    *reinterpret_cast<uint2*>(&zhi[(size_t)row * DIM + lane * 4]) = hp;
    *reinterpret_cast<uint2*>(&zlo[(size_t)row * DIM + lane * 4]) = lp;

    #pragma unroll
    for (int off = 32; off > 0; off >>= 1) s += __shfl_down(s, off);
    if (lane == 0) norms[row] = s;
}

// unrank upper-triangular pair index p -> (I, J), I <= J
__device__ __forceinline__ void unrank(int p, int& I, int& J) {
    I = (int)(NTILE + 0.5 - sqrt((NTILE + 0.5) * (NTILE + 0.5) - 2.0 * p));
    int base = I * NTILE - I * (I - 1) / 2;
    if (p < base)                     { --I; base = I * NTILE - I * (I - 1) / 2; }
    else if (p >= base + (NTILE - I)) { ++I; base = I * NTILE - I * (I - 1) / 2; }
    J = I + (p - base);
}

// ---------- main gram kernel: pre-split operands, global_load_lds staging ----------
__global__ __launch_bounds__(256, 3) void mmd_gram_pre(const ushort* __restrict__ zhi,
                                                       const ushort* __restrict__ zlo,
                                                       const float* __restrict__ norms,
                                                       double* __restrict__ partials) {
    int I, J;
    unrank(blockIdx.x, I, J);

    __shared__ ushort hiI[TILE][BK], loI[TILE][BK];   // [point][k], 8 KB each
    __shared__ ushort hiJ[TILE][BK], loJ[TILE][BK];
    __shared__ double wsum[4];

    const int t   = threadIdx.x;
    const int l   = t & 63;
    const int wid = t >> 6;
    const int wy  = (wid >> 1) * 64;     // wave output-tile origin (rows)
    const int wx  = (wid & 1) * 64;      // (cols)

    // staging role per wave: {hiI, loI, hiJ, loJ}; 8 issues of 16 rows each/K-step
    const ushort* gsrc    = (wid & 1) ? zlo : zhi;
    const int     tileIdx = (wid < 2) ? I : J;
    ushort* lbase = (wid == 0) ? &hiI[0][0] : (wid == 1) ? &loI[0][0]
                  : (wid == 2) ? &hiJ[0][0] : &loJ[0][0];
    // lane l covers row (l>>2) of each 16-row group, 16B chunk (l&3) of the 64B row
    const ushort* growl = gsrc + (size_t)(tileIdx * TILE + (l >> 2)) * DIM + (l & 3) * 8;

    f32x4 acc[4][4];
    #pragma unroll
    for (int bi = 0; bi < 4; ++bi)
        #pragma unroll
        for (int bj = 0; bj < 4; ++bj)
            acc[bi][bj] = (f32x4)0.0f;

    const int ar = l & 15;            // frag point-within-16 (A row / B col)
    const int ac = (l >> 4) * 8;      // frag k-chunk: 8 contiguous bf16

    for (int k0 = 0; k0 < DIM; k0 += BK) {
        __syncthreads();              // previous chunk fully consumed by all waves
        #pragma unroll
        for (int g = 0; g < 8; ++g)
            GLDS(growl + (size_t)g * 16 * DIM + k0, lbase + g * 16 * BK);
        __syncthreads();              // vmcnt(0) drain before barrier (compiler)

        bf16x8 aHi[4], aLo[4];
        #pragma unroll
        for (int bi = 0; bi < 4; ++bi) {
            aHi[bi] = *reinterpret_cast<const bf16x8*>(&hiI[wy + bi * 16 + ar][ac]);
            aLo[bi] = *reinterpret_cast<const bf16x8*>(&loI[wy + bi * 16 + ar][ac]);
        }
        #pragma unroll
        for (int bj = 0; bj < 4; ++bj) {
            bf16x8 bHi = *reinterpret_cast<const bf16x8*>(&hiJ[wx + bj * 16 + ar][ac]);
            bf16x8 bLo = *reinterpret_cast<const bf16x8*>(&loJ[wx + bj * 16 + ar][ac]);
            #pragma unroll
            for (int bi = 0; bi < 4; ++bi) {
                acc[bi][bj] = __builtin_amdgcn_mfma_f32_16x16x32_bf16(aHi[bi], bHi, acc[bi][bj], 0, 0, 0);
                acc[bi][bj] = __builtin_amdgcn_mfma_f32_16x16x32_bf16(aHi[bi], bLo, acc[bi][bj], 0, 0, 0);
                acc[bi][bj] = __builtin_amdgcn_mfma_f32_16x16x32_bf16(aLo[bi], bHi, acc[bi][bj], 0, 0, 0);
            }
        }
    }

    // epilogue: sq = ||zi||² + ||zj||² - 2·dot ; C/D map: col=l&15, row=(l>>4)*4+reg
    const int rg = (l >> 4) * 4;
    double tsum = 0.0;
    #pragma unroll
    for (int bi = 0; bi < 4; ++bi) {
        float ni[4];
        #pragma unroll
        for (int r = 0; r < 4; ++r)
            ni[r] = norms[I * TILE + wy + bi * 16 + rg + r];
        #pragma unroll
        for (int bj = 0; bj < 4; ++bj) {
            const float nj = norms[J * TILE + wx + bj * 16 + (l & 15)];
            #pragma unroll
            for (int r = 0; r < 4; ++r) {
                float sq = ni[r] + nj - 2.0f * acc[bi][bj][r];
                tsum += (double)__expf(sq * (-1.0f / 65536.0f));
            }
        }
    }

    const double sgn  = ((I < XTILE) == (J < XTILE)) ? 1.0 : -1.0;
    const double mult = (I == J) ? sgn : 2.0 * sgn;   // off-diag tiles count twice
    tsum *= mult;

    #pragma unroll
    for (int off = 32; off > 0; off >>= 1) tsum += __shfl_down(tsum, off);
    if (l == 0) wsum[wid] = tsum;
    __syncthreads();
    if (t == 0) partials[blockIdx.x] = wsum[0] + wsum[1] + wsum[2] + wsum[3];
}

// ---------- fallback path (scratch too small): convert inside the K-loop ----------
__global__ __launch_bounds__(256) void mmd_norms(const float* __restrict__ a,
                                                 const float* __restrict__ b,
                                                 float* __restrict__ norms) {
    const int row  = blockIdx.x * 4 + (threadIdx.x >> 6);
    const int lane = threadIdx.x & 63;
    const float* src = (row < NPTS) ? (a + (size_t)row * DIM)
                                    : (b + (size_t)(row - NPTS) * DIM);
    float4 v = *reinterpret_cast<const float4*>(src + lane * 4);
    float s = v.x * v.x + v.y * v.y + v.z * v.z + v.w * v.w;
    #pragma unroll
    for (int off = 32; off > 0; off >>= 1) s += __shfl_down(s, off);
    if (lane == 0) norms[row] = s;
}

__device__ __forceinline__ void conv_write(float4 v, ushort* hidst, ushort* lodst) {
    uint hx = __float_as_uint(v.x) & 0xFFFF0000u, hy = __float_as_uint(v.y) & 0xFFFF0000u,
         hz = __float_as_uint(v.z) & 0xFFFF0000u, hw = __float_as_uint(v.w) & 0xFFFF0000u;
    float lxf = v.x - __uint_as_float(hx), lyf = v.y - __uint_as_float(hy),
          lzf = v.z - __uint_as_float(hz), lwf = v.w - __uint_as_float(hw);
    *reinterpret_cast<uint2*>(hidst) = make_uint2((hx >> 16) | hy, (hz >> 16) | hw);
    *reinterpret_cast<uint2*>(lodst) =
        make_uint2((__float_as_uint(lxf) >> 16) | (__float_as_uint(lyf) & 0xFFFF0000u),
                   (__float_as_uint(lzf) >> 16) | (__float_as_uint(lwf) & 0xFFFF0000u));
}

__global__ __launch_bounds__(256, 3) void mmd_gram_fly(const float* __restrict__ a,
                                                       const float* __restrict__ b,
                                                       const float* __restrict__ norms,
                                                       double* __restrict__ partials) {
    int I, J;
    unrank(blockIdx.x, I, J);

    __shared__ ushort hiI[TILE][BK], loI[TILE][BK];
    __shared__ ushort hiJ[TILE][BK], loJ[TILE][BK];
    __shared__ double wsum[4];

    const int t = threadIdx.x, l = t & 63, wid = t >> 6;
    const int wy = (wid >> 1) * 64, wx = (wid & 1) * 64;

    const float* srcI = (I < XTILE) ? (a + (size_t)I * TILE * DIM)
                                    : (b + (size_t)(I - XTILE) * TILE * DIM);
    const float* srcJ = (J < XTILE) ? (a + (size_t)J * TILE * DIM)
                                    : (b + (size_t)(J - XTILE) * TILE * DIM);

    f32x4 acc[4][4];
    #pragma unroll
    for (int bi = 0; bi < 4; ++bi)
        #pragma unroll
        for (int bj = 0; bj < 4; ++bj) acc[bi][bj] = (f32x4)0.0f;

    const int srow = t >> 3, skf = (t & 7) * 4;
    const int ar = l & 15, ac = (l >> 4) * 8;

    for (int k0 = 0; k0 < DIM; k0 += BK) {
        __syncthreads();
        float4 vI[4], vJ[4];
        #pragma unroll
        for (int q = 0; q < 4; ++q) {
            vI[q] = *reinterpret_cast<const float4*>(srcI + (size_t)(srow + 32 * q) * DIM + k0 + skf);
            vJ[q] = *reinterpret_cast<const float4*>(srcJ + (size_t)(srow + 32 * q) * DIM + k0 + skf);
        }
        #pragma unroll
        for (int q = 0; q < 4; ++q) {
            const int r = srow + 32 * q;
            conv_write(vI[q], &hiI[r][skf], &loI[r][skf]);
            conv_write(vJ[q], &hiJ[r][skf], &loJ[r][skf]);
        }
        __syncthreads();

        bf16x8 aHi[4], aLo[4];
        #pragma unroll
        for (int bi = 0; bi < 4; ++bi) {
            aHi[bi] = *reinterpret_cast<const bf16x8*>(&hiI[wy + bi * 16 + ar][ac]);
            aLo[bi] = *reinterpret_cast<const bf16x8*>(&loI[wy + bi * 16 + ar][ac]);
        }
        #pragma unroll
        for (int bj = 0; bj < 4; ++bj) {
            bf16x8 bHi = *reinterpret_cast<const bf16x8*>(&hiJ[wx + bj * 16 + ar][ac]);
            bf16x8 bLo = *reinterpret_cast<const bf16x8*>(&loJ[wx + bj * 16 + ar][ac]);
            #pragma unroll
            for (int bi = 0; bi < 4; ++bi) {
                acc[bi][bj] = __builtin_amdgcn_mfma_f32_16x16x32_bf16(aHi[bi], bHi, acc[bi][bj], 0, 0, 0);
                acc[bi][bj] = __builtin_amdgcn_mfma_f32_16x16x32_bf16(aHi[bi], bLo, acc[bi][bj], 0, 0, 0);
                acc[bi][bj] = __builtin_amdgcn_mfma_f32_16x16x32_bf16(aLo[bi], bHi, acc[bi][bj], 0, 0, 0);
            }
        }
    }

    const int rg = (l >> 4) * 4;
    double tsum = 0.0;
    #pragma unroll
    for (int bi = 0; bi < 4; ++bi) {
        float ni[4];
        #pragma unroll
        for (int r = 0; r < 4; ++r) ni[r] = norms[I * TILE + wy + bi * 16 + rg + r];
        #pragma unroll
        for (int bj = 0; bj < 4; ++bj) {
            const float nj = norms[J * TILE + wx + bj * 16 + (l & 15)];
            #pragma unroll
            for (int r = 0; r < 4; ++r) {
                float sq = ni[r] + nj - 2.0f * acc[bi][bj][r];
                tsum += (double)__expf(sq * (-1.0f / 65536.0f));
            }
        }
    }

    const double sgn  = ((I < XTILE) == (J < XTILE)) ? 1.0 : -1.0;
    const double mult = (I == J) ? sgn : 2.0 * sgn;
    tsum *= mult;

    #pragma unroll
    for (int off = 32; off > 0; off >>= 1) tsum += __shfl_down(tsum, off);
    if (l == 0) wsum[wid] = tsum;
    __syncthreads();
    if (t == 0) partials[blockIdx.x] = wsum[0] + wsum[1] + wsum[2] + wsum[3];
}

__global__ __launch_bounds__(256) void mmd_reduce(const double* __restrict__ partials,
                                                  float* __restrict__ out) {
    double s = 0.0;
    for (int i = threadIdx.x; i < NTRI; i += 256) s += partials[i];
    #pragma unroll
    for (int off = 32; off > 0; off >>= 1) s += __shfl_down(s, off);
    __shared__ double wsum[4];
    const int wid = threadIdx.x >> 6, lane = threadIdx.x & 63;
    if (lane == 0) wsum[wid] = s;
    __syncthreads();
    if (threadIdx.x == 0)
        out[0] = (float)((wsum[0] + wsum[1] + wsum[2] + wsum[3]) /
                         ((double)NPTS * (double)NPTS));
}

extern "C" void kernel_launch(void* const* d_in, const int* in_sizes, int n_in,
                              void* d_out, int out_size, void* d_ws, size_t ws_size,
                              hipStream_t stream) {
    const float* a = (const float*)d_in[0];
    const float* b = (const float*)d_in[1];
    float* out = (float*)d_out;

    const size_t zElems = (size_t)MTOT * DIM;
    const size_t need = zElems * 2 * sizeof(ushort)       // zhi + zlo (16 MB)
                      + (size_t)MTOT * sizeof(float)      // norms
                      + (size_t)NTRI * sizeof(double);    // partials

    if (ws_size >= need) {
        ushort* zhi   = (ushort*)d_ws;
        ushort* zlo   = zhi + zElems;
        float*  norms = (float*)(zlo + zElems);
        double* partials = (double*)(norms + MTOT);
        mmd_prep<<<MTOT / 4, 256, 0, stream>>>(a, b, zhi, zlo, norms);
        mmd_gram_pre<<<NTRI, 256, 0, stream>>>(zhi, zlo, norms, partials);
        mmd_reduce<<<1, 256, 0, stream>>>(partials, out);
    } else {
        float*  norms    = (float*)d_ws;
        double* partials = (double*)((char*)d_ws + (size_t)MTOT * sizeof(float));
        mmd_norms<<<MTOT / 4, 256, 0, stream>>>(a, b, norms);
        mmd_gram_fly<<<NTRI, 256, 0, stream>>>(a, b, norms, partials);
        mmd_reduce<<<1, 256, 0, stream>>>(partials, out);
    }
}

// Round 5
// 158.414 us; speedup vs baseline: 1.7643x; 1.7643x over previous
//
#include <hip/hip_runtime.h>
#include <math.h>

// MMD loss via single-bf16 MFMA (RN-rounded hi parts) + exact fp32 norms.
// N²·MMD = Σ_{i,j} s_i s_j exp(-||z_i - z_j||²/D²), z = [a;b], s = [+1;-1].
// Signed Gram sum symmetric => upper-triangular 128x128 tiles (off-diag ×2).
// sq = n_i + n_j - 2·dot_bf16; per-entry exp-arg err ~2.7e-6 random sign,
// mean bias ~1e-9 (partially cancelling across xx/yy/xy). Norms exact fp32.
// LDS: BK=64 (128 B rows) with XOR chunk-swizzle chunk^=(row&7), applied
// both-sides (pre-swizzled global source for global_load_lds linear writes,
// same XOR on ds_read) -> 2-way bank aliasing (free) instead of 16-way.

#define NPTS  8192
#define DIM   256
#define MTOT  (2 * NPTS)                  // 16384
#define TILE  128
#define BK    64                          // k per step; LDS row = 128 B = 8 chunks
#define NTILE (MTOT / TILE)               // 128
#define XTILE (NPTS / TILE)               // 64: tiles [0,64) are 'a', rest 'b'
#define NTRI  (NTILE * (NTILE + 1) / 2)   // 8256

typedef short bf16x8 __attribute__((ext_vector_type(8)));   // 8 bf16 = 4 VGPR
typedef float f32x4  __attribute__((ext_vector_type(4)));   // MFMA C/D

// async global->LDS, 16B/lane; LDS dest = wave-uniform base + lane*16 (HW)
#define GLDS(g, l)                                                          \
    __builtin_amdgcn_global_load_lds(                                       \
        (const __attribute__((address_space(1))) void*)(g),                 \
        (__attribute__((address_space(3))) void*)(l), 16, 0, 0)

__device__ __forceinline__ uint rn_bf16(float x) {   // round-to-nearest-even bf16
    uint u = __float_as_uint(x);
    return (u + 0x7FFFu + ((u >> 16) & 1u)) >> 16;
}

// ---------- prep: fp32 -> bf16 (RN) + exact fp32 norms ----------
__global__ __launch_bounds__(256) void mmd_prep(const float* __restrict__ a,
                                                const float* __restrict__ b,
                                                ushort* __restrict__ zh,
                                                float* __restrict__ norms) {
    const int row  = blockIdx.x * 4 + (threadIdx.x >> 6);   // one wave per row
    const int lane = threadIdx.x & 63;
    const float* src = (row < NPTS) ? (a + (size_t)row * DIM)
                                    : (b + (size_t)(row - NPTS) * DIM);
    float4 v = *reinterpret_cast<const float4*>(src + lane * 4);
    float s = v.x * v.x + v.y * v.y + v.z * v.z + v.w * v.w;

    uint2 packed = make_uint2(rn_bf16(v.x) | (rn_bf16(v.y) << 16),
                              rn_bf16(v.z) | (rn_bf16(v.w) << 16));
    *reinterpret_cast<uint2*>(&zh[(size_t)row * DIM + lane * 4]) = packed;

    #pragma unroll
    for (int off = 32; off > 0; off >>= 1) s += __shfl_down(s, off);
    if (lane == 0) norms[row] = s;
}

// unrank upper-triangular pair index p -> (I, J), I <= J
__device__ __forceinline__ void unrank(int p, int& I, int& J) {
    I = (int)(NTILE + 0.5 - sqrt((NTILE + 0.5) * (NTILE + 0.5) - 2.0 * p));
    int base = I * NTILE - I * (I - 1) / 2;
    if (p < base)                     { --I; base = I * NTILE - I * (I - 1) / 2; }
    else if (p >= base + (NTILE - I)) { ++I; base = I * NTILE - I * (I - 1) / 2; }
    J = I + (p - base);
}

// ---------- gram: single-product bf16, swizzled LDS, global_load_lds ----------
__global__ __launch_bounds__(256, 3) void mmd_gram(const ushort* __restrict__ zh,
                                                   const float* __restrict__ norms,
                                                   double* __restrict__ partials) {
    int I, J;
    unrank(blockIdx.x, I, J);

    __shared__ ushort sI[TILE * BK];   // 16 KB each, XOR-swizzled chunk layout
    __shared__ ushort sJ[TILE * BK];
    __shared__ double wsum[4];

    const int t   = threadIdx.x;
    const int l   = t & 63;
    const int wid = t >> 6;
    const int wy  = (wid >> 1) * 64;    // wave output-tile origin (rows in I)
    const int wx  = (wid & 1) * 64;     // (cols in J)

    // staging: waves 0-1 -> I-tile rows [0,64)/[64,128); waves 2-3 -> J-tile
    const int    rbase = (wid & 1) * 64;
    const ushort* gtile = zh + (size_t)(((wid < 2) ? I : J) * TILE) * DIM;
    ushort*       ltile = (wid < 2) ? sI : sJ;
    // lane l: row (l>>3) within 8-row group, LDS chunk (l&7);
    // global chunk = (l&7) ^ (l>>3)  [row&7 == l>>3] -- the swizzle pre-permutation
    const int lrow = l >> 3;
    const int gch  = (l & 7) ^ lrow;
    const ushort* gsrc = gtile + (size_t)(rbase + lrow) * DIM + gch * 8;
    ushort*       ldst = ltile + (size_t)(rbase) * BK + (size_t)l * 8;

    f32x4 acc[4][4];
    #pragma unroll
    for (int bi = 0; bi < 4; ++bi)
        #pragma unroll
        for (int bj = 0; bj < 4; ++bj)
            acc[bi][bj] = (f32x4)0.0f;

    const int ar = l & 15;     // frag row-within-16 (A row / B col)
    const int cc = l >> 4;     // frag k-chunk group 0..3
    const int sw = ar & 7;     // read-side XOR (row&7 == ar&7)

    for (int k0 = 0; k0 < DIM; k0 += BK) {
        __syncthreads();       // previous chunk fully consumed by all waves
        #pragma unroll
        for (int g = 0; g < 8; ++g)     // 8 issues x 8 rows x 128 B
            GLDS(gsrc + (size_t)g * 8 * DIM + k0, ldst + (size_t)g * 8 * BK);
        __syncthreads();       // compiler drains vmcnt(0) before barrier

        #pragma unroll
        for (int s = 0; s < 2; ++s) {   // two 16x16x32 k-subtiles of BK=64
            bf16x8 aF[4];
            #pragma unroll
            for (int bi = 0; bi < 4; ++bi) {
                const int rI = wy + bi * 16 + ar;
                const int ch = (s * 4 + cc) ^ sw;
                aF[bi] = *reinterpret_cast<const bf16x8*>(&sI[rI * BK + ch * 8]);
            }
            #pragma unroll
            for (int bj = 0; bj < 4; ++bj) {
                const int rJ = wx + bj * 16 + ar;
                const int ch = (s * 4 + cc) ^ sw;
                bf16x8 bF = *reinterpret_cast<const bf16x8*>(&sJ[rJ * BK + ch * 8]);
                #pragma unroll
                for (int bi = 0; bi < 4; ++bi)
                    acc[bi][bj] = __builtin_amdgcn_mfma_f32_16x16x32_bf16(
                                      aF[bi], bF, acc[bi][bj], 0, 0, 0);
            }
        }
    }

    // epilogue: sq = n_i + n_j - 2·dot ; C/D map: col=l&15, row=(l>>4)*4+reg
    const int rg = (l >> 4) * 4;
    double tsum = 0.0;
    #pragma unroll
    for (int bi = 0; bi < 4; ++bi) {
        float ni[4];
        #pragma unroll
        for (int r = 0; r < 4; ++r)
            ni[r] = norms[I * TILE + wy + bi * 16 + rg + r];
        #pragma unroll
        for (int bj = 0; bj < 4; ++bj) {
            const float nj = norms[J * TILE + wx + bj * 16 + (l & 15)];
            #pragma unroll
            for (int r = 0; r < 4; ++r) {
                float sq = ni[r] + nj - 2.0f * acc[bi][bj][r];
                tsum += (double)__expf(sq * (-1.0f / 65536.0f));
            }
        }
    }

    const double sgn  = ((I < XTILE) == (J < XTILE)) ? 1.0 : -1.0;
    const double mult = (I == J) ? sgn : 2.0 * sgn;   // off-diag tiles count twice
    tsum *= mult;

    #pragma unroll
    for (int off = 32; off > 0; off >>= 1) tsum += __shfl_down(tsum, off);
    if (l == 0) wsum[wid] = tsum;
    __syncthreads();
    if (t == 0) partials[blockIdx.x] = wsum[0] + wsum[1] + wsum[2] + wsum[3];
}

__global__ __launch_bounds__(256) void mmd_reduce(const double* __restrict__ partials,
                                                  float* __restrict__ out) {
    double s = 0.0;
    for (int i = threadIdx.x; i < NTRI; i += 256) s += partials[i];
    #pragma unroll
    for (int off = 32; off > 0; off >>= 1) s += __shfl_down(s, off);
    __shared__ double wsum[4];
    const int wid = threadIdx.x >> 6, lane = threadIdx.x & 63;
    if (lane == 0) wsum[wid] = s;
    __syncthreads();
    if (threadIdx.x == 0)
        out[0] = (float)((wsum[0] + wsum[1] + wsum[2] + wsum[3]) /
                         ((double)NPTS * (double)NPTS));
}

extern "C" void kernel_launch(void* const* d_in, const int* in_sizes, int n_in,
                              void* d_out, int out_size, void* d_ws, size_t ws_size,
                              hipStream_t stream) {
    const float* a = (const float*)d_in[0];
    const float* b = (const float*)d_in[1];
    float* out = (float*)d_out;

    const size_t zElems = (size_t)MTOT * DIM;
    ushort* zh    = (ushort*)d_ws;                     // 8 MB
    float*  norms = (float*)(zh + zElems);             // 64 KB
    double* partials = (double*)(norms + MTOT);        // NTRI * 8 B

    mmd_prep<<<MTOT / 4, 256, 0, stream>>>(a, b, zh, norms);
    mmd_gram<<<NTRI, 256, 0, stream>>>(zh, norms, partials);
    mmd_reduce<<<1, 256, 0, stream>>>(partials, out);
}